// Round 4
// baseline (22.494 us; speedup 1.0000x reference)
//
#include <hip/hip_runtime.h>

#define HH 128
#define WW 192
#define HW (HH * WW)

typedef float f32x4 __attribute__((ext_vector_type(4)));

__device__ __forceinline__ f32x4 vfma(f32x4 a, f32x4 b, f32x4 c) {
    return __builtin_elementwise_fma(a, b, c);
}
__device__ __forceinline__ f32x4 splat(float s) { return (f32x4){s, s, s, s}; }
__device__ __forceinline__ f32x4 vrelu(f32x4 v) {
    return __builtin_elementwise_max(v, (f32x4){0.f, 0.f, 0.f, 0.f});
}
__device__ __forceinline__ float relu(float v) { return fmaxf(v, 0.0f); }

// Per-wave weight slice layout (176 floats, 16B-aligned rows):
// [0..7] w0x[o]  [8..15] w0y[o]  [16..23] b0[o]
// [24..87] w0t[ch][o]  [88..151] w1t[i][o]
// [152..159] w2[o]  [160..167] b1[o]  [168] b2

__global__ __launch_bounds__(512, 4) void dmh_kernel(
    const float* __restrict__ mask_feats,   // (4,8,128,192)
    const float* __restrict__ params,       // (128,169)
    const float* __restrict__ locs,         // (128,2)
    const float* __restrict__ soi,          // (5,)
    const int*   __restrict__ im_inds,      // (128,)
    const int*   __restrict__ fpn_levels,   // (128,)
    const int*   __restrict__ stride_p,     // scalar (=8)
    float*       __restrict__ out)          // (128,1,256,384)
{
    const int tid = threadIdx.x;
    const int c0 = blockIdx.x * 64;   // source col tile origin
    const int r0 = blockIdx.y * 32;   // source row tile origin
    const int n  = blockIdx.z;        // instance

    __shared__ float sW[8 * 176];     // per-wave weight slices (no barrier needed)
    __shared__ float tile[33 * 66];   // rows -1..31 -> 0..32, cols -1..63 -> 0..64

    const int wid  = tid >> 6;
    const int lane = tid & 63;
    float* __restrict__ sWb = &sW[wid * 176];
    const float* __restrict__ P = params + (size_t)n * 169;

    // ---- issue weight loads first (3 per lane, oldest in vmcnt queue) ----
    float wval[3];
    #pragma unroll
    for (int k = 0; k < 3; ++k) {
        int idx = lane + 64 * k;
        wval[k] = (idx < 169) ? P[idx] : 0.0f;
    }

    const int   stride = *stride_p;                 // 8
    const float half   = 0.5f * (float)stride;      // 4.0
    const float locx = locs[2 * n + 0];
    const float locy = locs[2 * n + 1];
    const float inv  = 1.0f / soi[fpn_levels[n]];
    const float* fb  = mask_feats + (size_t)im_inds[n] * 8 * HW;

    // ---- interior thread geometry + feat loads (behind weight loads) ----
    const int ir = tid >> 4;          // 0..31
    const int ic = (tid & 15) << 2;   // 0,4,...,60
    const int rr = r0 + ir, cc = c0 + ic;   // always in-bounds
    const float* fp = fb + rr * WW + cc;

    f32x4 xv[8];
    #pragma unroll
    for (int ch = 0; ch < 8; ++ch)
        xv[ch] = *reinterpret_cast<const f32x4*>(fp + ch * HW);

    // ---- scatter weights into this wave's LDS slice (transposed layout) ----
    #pragma unroll
    for (int k = 0; k < 3; ++k) {
        int idx = lane + 64 * k;
        if (idx < 169) {
            int d;
            if (idx < 80)       { int o = idx / 10, r = idx - o * 10;
                                  d = (r == 0) ? o : (r == 1) ? (8 + o) : (24 + (r - 2) * 8 + o); }
            else if (idx < 144) { int t = idx - 80, o = t >> 3, i = t & 7; d = 88 + i * 8 + o; }
            else if (idx < 152) d = 152 + (idx - 144);
            else if (idx < 160) d = 16 + (idx - 152);
            else if (idx < 168) d = 160 + (idx - 160);
            else                d = 168;
            sWb[d] = wval[k];
        }
    }
    // same-wave ds_write -> ds_read: lgkmcnt ordering only, no __syncthreads.

    // ---------- phase 1a: interior 32x64, 4 contiguous px per thread ----------
    {
        const float rxd = -(float)stride * inv;
        float rx0 = (locx - (float)(cc * stride) - half) * inv;
        f32x4 rx4 = {rx0, rx0 + rxd, rx0 + 2.f * rxd, rx0 + 3.f * rxd};
        const float ry = (locy - (float)(rr * stride) - half) * inv;

        f32x4 h[8];
        #pragma unroll
        for (int o = 0; o < 8; ++o) {
            float t = fmaf(sWb[8 + o], ry, sWb[16 + o]);
            h[o] = vfma(splat(sWb[o]), rx4, splat(t));
        }
        #pragma unroll
        for (int ch = 0; ch < 8; ++ch) {
            float4 wlo = *reinterpret_cast<const float4*>(&sWb[24 + ch * 8]);
            float4 whi = *reinterpret_cast<const float4*>(&sWb[28 + ch * 8]);
            float wv[8] = {wlo.x, wlo.y, wlo.z, wlo.w, whi.x, whi.y, whi.z, whi.w};
            #pragma unroll
            for (int o = 0; o < 8; ++o)
                h[o] = vfma(splat(wv[o]), xv[ch], h[o]);
        }

        f32x4 a[8];
        #pragma unroll
        for (int o = 0; o < 8; ++o) a[o] = splat(sWb[160 + o]);
        #pragma unroll
        for (int i = 0; i < 8; ++i) {
            float4 wlo = *reinterpret_cast<const float4*>(&sWb[88 + i * 8]);
            float4 whi = *reinterpret_cast<const float4*>(&sWb[92 + i * 8]);
            float wv[8] = {wlo.x, wlo.y, wlo.z, wlo.w, whi.x, whi.y, whi.z, whi.w};
            f32x4 v = vrelu(h[i]);
            #pragma unroll
            for (int o = 0; o < 8; ++o)
                a[o] = vfma(splat(wv[o]), v, a[o]);
        }

        f32x4 lg = splat(sWb[168]);
        #pragma unroll
        for (int o = 0; o < 8; ++o)
            lg = vfma(splat(sWb[152 + o]), vrelu(a[o]), lg);

        #pragma unroll
        for (int j = 0; j < 4; ++j)
            tile[(ir + 1) * 66 + ic + 1 + j] = lg[j];
    }

    // ---------- phase 1b: 97 halo px (row -1, col -1), scalar ----------
    if (tid < 97) {
        int r, c;
        if (tid < 65) { r = -1; c = tid - 1; }      // row -1, cols -1..63
        else          { r = tid - 65; c = -1; }     // rows 0..31, col -1
        int hr = min(max(r0 + r, 0), HH - 1);
        int hc = min(max(c0 + c, 0), WW - 1);
        const float* hfp = fb + hr * WW + hc;
        float rx  = (locx - (float)(hc * stride) - half) * inv;
        float ry2 = (locy - (float)(hr * stride) - half) * inv;
        float hh[8];
        #pragma unroll
        for (int o = 0; o < 8; ++o)
            hh[o] = fmaf(sWb[o], rx, fmaf(sWb[8 + o], ry2, sWb[16 + o]));
        #pragma unroll
        for (int ch = 0; ch < 8; ++ch) {
            float x = hfp[ch * HW];
            #pragma unroll
            for (int o = 0; o < 8; ++o) hh[o] = fmaf(sWb[24 + ch * 8 + o], x, hh[o]);
        }
        float aa[8];
        #pragma unroll
        for (int o = 0; o < 8; ++o) aa[o] = sWb[160 + o];
        #pragma unroll
        for (int i = 0; i < 8; ++i) {
            float v = relu(hh[i]);
            #pragma unroll
            for (int o = 0; o < 8; ++o) aa[o] = fmaf(sWb[88 + i * 8 + o], v, aa[o]);
        }
        float lg = sWb[168];
        #pragma unroll
        for (int o = 0; o < 8; ++o) lg = fmaf(sWb[152 + o], relu(aa[o]), lg);
        tile[(r + 1) * 66 + (c + 1)] = lg;
    }
    __syncthreads();

    // ---------- phase 2: x2 aligned upsample -> 64x128 output tile ----------
    const int kx = tid & 31;          // 32 groups of 4 output cols
    const int ky = tid >> 5;          // 16 row groups of 4 rows
    float* ob = out + ((size_t)n * 256 + 2 * r0) * 384 + 2 * c0 + 4 * kx;
    #pragma unroll
    for (int yy = 0; yy < 4; ++yy) {
        int yt = ky * 4 + yy;         // 0..63
        int i  = 2 * r0 + yt - 1;
        int rb = i >> 1;              // arithmetic shift handles i=-1
        int fy = i & 1;
        float wy0 = fy ? 0.5f : 1.0f;
        float wy1 = fy ? 0.5f : 0.0f;
        int lr  = rb - r0 + 1;        // in [0,32]
        int lr2 = lr + fy;            // in [0,32]
        const float* ra = &tile[lr  * 66 + 2 * kx];
        const float* rc = &tile[lr2 * 66 + 2 * kx];
        float t0 = fmaf(wy1, rc[0], wy0 * ra[0]);
        float t1 = fmaf(wy1, rc[1], wy0 * ra[1]);
        float t2 = fmaf(wy1, rc[2], wy0 * ra[2]);
        float4 o4;
        o4.x = 0.5f * (t0 + t1);
        o4.y = t1;
        o4.z = 0.5f * (t1 + t2);
        o4.w = t2;
        *reinterpret_cast<float4*>(ob + (size_t)yt * 384) = o4;
    }
}

extern "C" void kernel_launch(void* const* d_in, const int* in_sizes, int n_in,
                              void* d_out, int out_size, void* d_ws, size_t ws_size,
                              hipStream_t stream) {
    const float* mask_feats = (const float*)d_in[0];
    const float* params     = (const float*)d_in[1];
    const float* locs       = (const float*)d_in[2];
    const float* soi        = (const float*)d_in[3];
    const int*   im_inds    = (const int*)d_in[4];
    const int*   fpn_levels = (const int*)d_in[5];
    const int*   stride_p   = (const int*)d_in[6];
    float* out = (float*)d_out;

    dim3 grid(WW / 64, HH / 32, 128);   // (3, 4, 128)
    dim3 block(512);
    dmh_kernel<<<grid, block, 0, stream>>>(
        mask_feats, params, locs, soi, im_inds, fpn_levels, stride_p, out);
}